// Round 9
// baseline (867.861 us; speedup 1.0000x reference)
//
#include <hip/hip_runtime.h>
#include <math.h>

#define DHID 2048
#define TOK 256
#define NHEAD 16
#define HDIM 128
#define NEXP 64
#define KSEL 8
#define FFD 1024
#define RMSEPS 1e-5f
#define ATTNSCALE 0.08838834764831845f

typedef short bf16x8 __attribute__((ext_vector_type(8)));
typedef float f32x4 __attribute__((ext_vector_type(4)));
typedef float f4 __attribute__((ext_vector_type(4)));

__device__ __forceinline__ unsigned short f2bf(float f){
  union { float f; unsigned int u; } c; c.f = f;
  unsigned int u = c.u + 0x7fffu + ((c.u>>16)&1u);
  return (unsigned short)(u>>16);
}
__device__ __forceinline__ unsigned int pk2(float a, float b){
  return (unsigned int)f2bf(a) | ((unsigned int)f2bf(b)<<16);
}
__device__ __forceinline__ bf16x8 as_bf8(uint4 u){
  union { uint4 u; bf16x8 v; } c; c.u = u; return c.v;
}

#define WAITV(N) { asm volatile("s_waitcnt vmcnt(" #N ")" ::: "memory"); __builtin_amdgcn_sched_barrier(0); }
#define WAITL0   { asm volatile("s_waitcnt lgkmcnt(0)" ::: "memory"); __builtin_amdgcn_sched_barrier(0); }
#define SB       __builtin_amdgcn_sched_barrier(0);

// ---------------- RMSNorm (bf16 out + optional f32 out) ----------------
__global__ __launch_bounds__(256) void rms_kernel(const float* __restrict__ x,
    const float* __restrict__ w, unsigned short* __restrict__ obf,
    float* __restrict__ of32)
{
  int row = blockIdx.x, tid = threadIdx.x;
  const float* xr = x + (size_t)row*DHID;
  float4 a = *(const float4*)(xr + tid*8);
  float4 b = *(const float4*)(xr + tid*8 + 4);
  float ss = a.x*a.x+a.y*a.y+a.z*a.z+a.w*a.w + b.x*b.x+b.y*b.y+b.z*b.z+b.w*b.w;
  #pragma unroll
  for(int o=32;o>0;o>>=1) ss += __shfl_down(ss,o);
  __shared__ float red[4];
  if((tid&63)==0) red[tid>>6]=ss;
  __syncthreads();
  float r = rsqrtf((red[0]+red[1]+red[2]+red[3])*(1.0f/DHID) + RMSEPS);
  float v[8] = {a.x,a.y,a.z,a.w,b.x,b.y,b.z,b.w};
  unsigned short ob[8];
  #pragma unroll
  for(int j=0;j<8;j++){
    float val = v[j]*r*w[tid*8+j];
    ob[j]=f2bf(val);
    if(of32) of32[(size_t)row*DHID + tid*8 + j] = val;
  }
  uint4 o4;
  o4.x = (unsigned int)ob[0] | ((unsigned int)ob[1]<<16);
  o4.y = (unsigned int)ob[2] | ((unsigned int)ob[3]<<16);
  o4.z = (unsigned int)ob[4] | ((unsigned int)ob[5]<<16);
  o4.w = (unsigned int)ob[6] | ((unsigned int)ob[7]<<16);
  *(uint4*)(obf + (size_t)row*DHID + tid*8) = o4;
}

// ---------------- RoPE cos/sin table [256][64] ----------------
__global__ void rope_table_kernel(float* __restrict__ cs, float* __restrict__ sn){
  int i = blockIdx.x*256 + threadIdx.x;  // 16384
  int s = i>>6, j = i&63;
  float invf = powf(10000.0f, -(float)j*(1.0f/64.0f));
  float ang = (float)s * invf;
  cs[i] = cosf(ang); sn[i] = sinf(ang);
}

// ---------------- fused QKV GEMM: C[s,o] = sum_d xn[s,d]*W[o,d] ----------------
__global__ __launch_bounds__(256) void gemm_qkv_kernel(
    const unsigned short* __restrict__ A,
    const float* __restrict__ qw, const float* __restrict__ kw, const float* __restrict__ vw,
    float* __restrict__ qo, float* __restrict__ ko, float* __restrict__ vo)
{
  int nt = blockIdx.x, mt = blockIdx.y;
  int which = nt>>5, nb = nt&31;
  const float* W = (which==0)? qw : (which==1)? kw : vw;
  float* OUT = (which==0)? qo : (which==1)? ko : vo;
  int n0 = nb*64, m0 = mt*64;
  __shared__ unsigned short As[64*64];
  __shared__ unsigned short Bs[64*64];
  int tid = threadIdx.x;
  int wid = tid>>6, lane = tid&63;
  int wm = wid>>1, wn = wid&1;
  int lr = lane&15, lg = lane>>4;
  int sr = tid>>2, sq = tid&3;
  f32x4 acc[2][2] = {};
  const unsigned short* Ap = A + (size_t)(m0+sr)*DHID + sq*16;
  const float* Bp = W + (size_t)(n0+sr)*DHID + sq*16;
  for(int k0=0;k0<DHID;k0+=64){
    uint4 a0 = *(const uint4*)(Ap + k0);
    uint4 a1 = *(const uint4*)(Ap + k0 + 8);
    float4 b0 = *(const float4*)(Bp + k0);
    float4 b1 = *(const float4*)(Bp + k0 + 4);
    float4 b2 = *(const float4*)(Bp + k0 + 8);
    float4 b3 = *(const float4*)(Bp + k0 + 12);
    int x7 = sr&7;
    *(uint4*)&As[sr*64 + (((sq*2)  ^ x7)*8)] = a0;
    *(uint4*)&As[sr*64 + (((sq*2+1)^ x7)*8)] = a1;
    uint4 p0 = make_uint4(pk2(b0.x,b0.y),pk2(b0.z,b0.w),pk2(b1.x,b1.y),pk2(b1.z,b1.w));
    uint4 p1 = make_uint4(pk2(b2.x,b2.y),pk2(b2.z,b2.w),pk2(b3.x,b3.y),pk2(b3.z,b3.w));
    *(uint4*)&Bs[sr*64 + (((sq*2)  ^ x7)*8)] = p0;
    *(uint4*)&Bs[sr*64 + (((sq*2+1)^ x7)*8)] = p1;
    __syncthreads();
    #pragma unroll
    for(int ki=0;ki<2;ki++){
      bf16x8 af[2], bfr[2];
      #pragma unroll
      for(int mi=0;mi<2;mi++){
        int r = wm*32 + mi*16 + lr;
        af[mi] = *(const bf16x8*)&As[r*64 + (((ki*4+lg)^(r&7))*8)];
      }
      #pragma unroll
      for(int ni=0;ni<2;ni++){
        int r = wn*32 + ni*16 + lr;
        bfr[ni] = *(const bf16x8*)&Bs[r*64 + (((ki*4+lg)^(r&7))*8)];
      }
      #pragma unroll
      for(int mi=0;mi<2;mi++)
        #pragma unroll
        for(int ni=0;ni<2;ni++)
          acc[mi][ni] = __builtin_amdgcn_mfma_f32_16x16x32_bf16(af[mi], bfr[ni], acc[mi][ni], 0,0,0);
    }
    __syncthreads();
  }
  #pragma unroll
  for(int mi=0;mi<2;mi++){
    #pragma unroll
    for(int ni=0;ni<2;ni++){
      int col = n0 + wn*32 + ni*16 + lr;
      int rowb = m0 + wm*32 + mi*16 + lg*4;
      #pragma unroll
      for(int rg=0;rg<4;rg++)
        OUT[(size_t)(rowb+rg)*DHID + col] = acc[mi][ni][rg];
    }
  }
}

// ---------------- O-proj GEMM (A f32->bf16 staged) + residual, dual store ----------------
__global__ __launch_bounds__(256) void gemm_o_kernel(const float* __restrict__ A,
  const float* __restrict__ W, const float* __restrict__ X,
  float* __restrict__ H, float* __restrict__ O)
{
  int nb = blockIdx.x, mt = blockIdx.y;
  int n0 = nb*64, m0 = mt*64;
  __shared__ unsigned short As[64*64];
  __shared__ unsigned short Bs[64*64];
  int tid = threadIdx.x;
  int wid = tid>>6, lane = tid&63;
  int wm = wid>>1, wn = wid&1;
  int lr = lane&15, lg = lane>>4;
  int sr = tid>>2, sq = tid&3;
  f32x4 acc[2][2] = {};
  const float* Ap = A + (size_t)(m0+sr)*DHID + sq*16;
  const float* Bp = W + (size_t)(n0+sr)*DHID + sq*16;
  for(int k0=0;k0<DHID;k0+=64){
    float4 a0=*(const float4*)(Ap+k0),   a1=*(const float4*)(Ap+k0+4);
    float4 a2=*(const float4*)(Ap+k0+8), a3=*(const float4*)(Ap+k0+12);
    float4 b0=*(const float4*)(Bp+k0),   b1=*(const float4*)(Bp+k0+4);
    float4 b2=*(const float4*)(Bp+k0+8), b3=*(const float4*)(Bp+k0+12);
    int x7 = sr&7;
    uint4 pa0 = make_uint4(pk2(a0.x,a0.y),pk2(a0.z,a0.w),pk2(a1.x,a1.y),pk2(a1.z,a1.w));
    uint4 pa1 = make_uint4(pk2(a2.x,a2.y),pk2(a2.z,a2.w),pk2(a3.x,a3.y),pk2(a3.z,a3.w));
    uint4 pb0 = make_uint4(pk2(b0.x,b0.y),pk2(b0.z,b0.w),pk2(b1.x,b1.y),pk2(b1.z,b1.w));
    uint4 pb1 = make_uint4(pk2(b2.x,b2.y),pk2(b2.z,b2.w),pk2(b3.x,b3.y),pk2(b3.z,b3.w));
    *(uint4*)&As[sr*64 + (((sq*2)  ^ x7)*8)] = pa0;
    *(uint4*)&As[sr*64 + (((sq*2+1)^ x7)*8)] = pa1;
    *(uint4*)&Bs[sr*64 + (((sq*2)  ^ x7)*8)] = pb0;
    *(uint4*)&Bs[sr*64 + (((sq*2+1)^ x7)*8)] = pb1;
    __syncthreads();
    #pragma unroll
    for(int ki=0;ki<2;ki++){
      bf16x8 af[2], bfr[2];
      #pragma unroll
      for(int mi=0;mi<2;mi++){
        int r = wm*32 + mi*16 + lr;
        af[mi] = *(const bf16x8*)&As[r*64 + (((ki*4+lg)^(r&7))*8)];
      }
      #pragma unroll
      for(int ni=0;ni<2;ni++){
        int r = wn*32 + ni*16 + lr;
        bfr[ni] = *(const bf16x8*)&Bs[r*64 + (((ki*4+lg)^(r&7))*8)];
      }
      #pragma unroll
      for(int mi=0;mi<2;mi++)
        #pragma unroll
        for(int ni=0;ni<2;ni++)
          acc[mi][ni] = __builtin_amdgcn_mfma_f32_16x16x32_bf16(af[mi], bfr[ni], acc[mi][ni], 0,0,0);
    }
    __syncthreads();
  }
  #pragma unroll
  for(int mi=0;mi<2;mi++){
    #pragma unroll
    for(int ni=0;ni<2;ni++){
      int col = n0 + wn*32 + ni*16 + lr;
      int rowb = m0 + wm*32 + mi*16 + lg*4;
      #pragma unroll
      for(int rg=0;rg<4;rg++){
        size_t idx = (size_t)(rowb+rg)*DHID + col;
        float v = acc[mi][ni][rg] + X[idx];
        H[idx] = v; O[idx] = v;
      }
    }
  }
}

// ---------------- QK RMSNorm (full 2048) + RoPE, f32 out [head][tok][128] ----------------
__global__ __launch_bounds__(256) void qknorm_rope_kernel(const float* __restrict__ in,
   const float* __restrict__ w, const float* __restrict__ cs, const float* __restrict__ sn,
   float* __restrict__ out)
{
  int t = blockIdx.x, tid = threadIdx.x;
  __shared__ float xs[DHID];
  const float* xr = in + (size_t)t*DHID;
  float4 a = *(const float4*)(xr + tid*8);
  float4 b = *(const float4*)(xr + tid*8 + 4);
  *(float4*)&xs[tid*8] = a; *(float4*)&xs[tid*8+4] = b;
  float ss = a.x*a.x+a.y*a.y+a.z*a.z+a.w*a.w + b.x*b.x+b.y*b.y+b.z*b.z+b.w*b.w;
  #pragma unroll
  for(int o=32;o>0;o>>=1) ss += __shfl_down(ss,o);
  __shared__ float red[4];
  if((tid&63)==0) red[tid>>6]=ss;
  __syncthreads();
  float r = rsqrtf((red[0]+red[1]+red[2]+red[3])*(1.0f/DHID) + RMSEPS);
  int hh = tid>>4, jb = (tid&15)*4;
  #pragma unroll
  for(int p=0;p<4;p++){
    int j = jb+p;
    int i0 = hh*HDIM + j, i1 = i0+64;
    float va = xs[i0]*r*w[i0];
    float vb = xs[i1]*r*w[i1];
    float c = cs[t*64+j], s = sn[t*64+j];
    out[((size_t)(hh*TOK + t))*HDIM + j]    = va*c - vb*s;
    out[((size_t)(hh*TOK + t))*HDIM + j+64] = vb*c + va*s;
  }
}

// ---------------- causal attention, f32, 16 q-rows per block (V read from [tok][D] direct) ----------------
__global__ __launch_bounds__(256) void attn_kernel(const float* __restrict__ qh,
  const float* __restrict__ kh, const float* __restrict__ vf, float* __restrict__ ctx)
{
  int head = blockIdx.x>>4, qt = blockIdx.x&15;
  __shared__ float qs[16][132];
  __shared__ float sc[16][260];
  __shared__ float red[16][16];
  __shared__ float rmx[16], rsm[16];
  int tid = threadIdx.x;
  {
    int r = tid>>4, c = (tid&15)*8;
    const float* src = qh + ((size_t)(head*TOK + qt*16 + r))*HDIM + c;
    *(float4*)&qs[r][c]   = *(const float4*)(src);
    *(float4*)&qs[r][c+4] = *(const float4*)(src+4);
  }
  __syncthreads();
  int qi = tid&15, kk = tid>>4;
  int qg = qt*16 + qi;
  for(int k=kk; k<=qg; k+=16){
    const float* kp = kh + ((size_t)(head*TOK + k))*HDIM;
    float d = 0.f;
    #pragma unroll 8
    for(int c=0;c<128;c+=4){
      float4 kv = *(const float4*)(kp + c);
      float4 qv = *(const float4*)&qs[qi][c];
      d += qv.x*kv.x + qv.y*kv.y + qv.z*kv.z + qv.w*kv.w;
    }
    sc[qi][k] = d*ATTNSCALE;
  }
  float m = -1e30f;
  for(int k=kk;k<=qg;k+=16) m = fmaxf(m, sc[qi][k]);
  red[qi][kk] = m;
  __syncthreads();
  if(kk==0){
    float mm=-1e30f;
    #pragma unroll
    for(int j=0;j<16;j++) mm = fmaxf(mm, red[qi][j]);
    rmx[qi]=mm;
  }
  __syncthreads();
  float mm = rmx[qi];
  float s = 0.f;
  for(int k=kk;k<=qg;k+=16){ float pp = expf(sc[qi][k]-mm); sc[qi][k]=pp; s+=pp; }
  red[qi][kk]=s;
  __syncthreads();
  if(kk==0){
    float t_=0.f;
    #pragma unroll
    for(int j=0;j<16;j++) t_ += red[qi][j];
    rsm[qi]=t_;
  }
  __syncthreads();
  int dg = kk;
  float acc[8]={0,0,0,0,0,0,0,0};
  const float* vp = vf + head*HDIM + dg*8;
  for(int k=0;k<=qg;k++){
    float p = sc[qi][k];
    float4 v0 = *(const float4*)(vp + (size_t)k*DHID);
    float4 v1 = *(const float4*)(vp + (size_t)k*DHID + 4);
    acc[0]+=p*v0.x; acc[1]+=p*v0.y; acc[2]+=p*v0.z; acc[3]+=p*v0.w;
    acc[4]+=p*v1.x; acc[5]+=p*v1.y; acc[6]+=p*v1.z; acc[7]+=p*v1.w;
  }
  float inv = 1.0f/rsm[qi];
  float* op = ctx + ((size_t)(qt*16+qi))*DHID + head*HDIM + dg*8;
  *(float4*)(op)   = make_float4(acc[0]*inv, acc[1]*inv, acc[2]*inv, acc[3]*inv);
  *(float4*)(op+4) = make_float4(acc[4]*inv, acc[5]*inv, acc[6]*inv, acc[7]*inv);
}

// ---------------- router: logits, softmax f32, exact top-8, expert lists ----------------
__global__ __launch_bounds__(256) void router_kernel(const float* __restrict__ hn,
    const float* __restrict__ rw, int* __restrict__ counts, int* __restrict__ toklist,
    float* __restrict__ wlist)
{
  int t = blockIdx.x, tid = threadIdx.x;
  __shared__ float xs[DHID];
  __shared__ float part[NEXP*4];
  __shared__ float probs[NEXP];
  *(float4*)&xs[tid*8]   = *(const float4*)(hn + (size_t)t*DHID + tid*8);
  *(float4*)&xs[tid*8+4] = *(const float4*)(hn + (size_t)t*DHID + tid*8+4);
  __syncthreads();
  int e = tid&63, c = tid>>6;
  const float* w = rw + (size_t)e*DHID + c*512;
  const float* xc = xs + c*512;
  float d = 0.f;
  for(int i=0;i<512;i+=4){
    float4 wv = *(const float4*)(w+i);
    d += xc[i]*wv.x + xc[i+1]*wv.y + xc[i+2]*wv.z + xc[i+3]*wv.w;
  }
  part[c*64 + e] = d;
  __syncthreads();
  if(tid<64){
    float logit = part[tid] + part[64+tid] + part[128+tid] + part[192+tid];
    float m = logit;
    #pragma unroll
    for(int o=32;o>0;o>>=1) m = fmaxf(m, __shfl_xor(m,o));
    float p = expf(logit - m);
    float s = p;
    #pragma unroll
    for(int o=32;o>0;o>>=1) s += __shfl_xor(s,o);
    probs[tid] = p/s;
  }
  __syncthreads();
  if(tid==0){
    unsigned long long used = 0ull;
    for(int r=0;r<KSEL;r++){
      float best = -1.f; int bi = 0;
      for(int j=0;j<NEXP;j++){
        if(!((used>>j)&1ull) && probs[j]>best){ best=probs[j]; bi=j; }
      }
      used |= (1ull<<bi);
      int slot = atomicAdd(&counts[bi],1);
      toklist[bi*TOK+slot] = t;
      wlist[bi*TOK+slot] = best;
    }
  }
}

// ---------------- MoE gate+up v9: 32x32 tile, BK=128, 16KB LDS, 4 blocks/CU ----------------
// Probe: does chip-wide load concurrency (2048 blocks, ~50% occupancy, 12
// in-flight loads/thread) break the 2.5 TB/s read plateau? Oldest-first FIFO:
// per slab issue order G(4),U(4),A(4); consumers wait via counted vmcnt(8).
__global__ __launch_bounds__(256,4) void moe_gateup_kernel(const unsigned short* __restrict__ hnb,
  const float* __restrict__ gw, const float* __restrict__ uw,
  const int* __restrict__ counts,
  const int* __restrict__ toklist, const float* __restrict__ wlist,
  unsigned short* __restrict__ mid)
{
  int fb = blockIdx.x, e = blockIdx.y, mc = blockIdx.z;   // fb: 32 F-rows
  int cnt = counts[e];
  if(mc*32 >= cnt) return;
  int tid = threadIdx.x;
  __shared__ int sbase;
  if(tid<64){
    int c = counts[tid];
    int v = c;
    #pragma unroll
    for(int o=1;o<64;o<<=1){ int n=__shfl_up(v,o); if(tid>=o) v+=n; }
    if(tid==e) sbase = v - c;
  }
  __shared__ unsigned short Gs[32*128];   // 8 KB
  __shared__ unsigned short Us[32*128];   // 8 KB
  int w = tid>>6, lane = tid&63;
  int wm = w>>1, wn = w&1, lr = lane&15, lg = lane>>4;
  int srow = tid>>3, u8 = tid&7;          // staging: 8 threads/row, 16 f32 each

  const float* Gp = gw + ((size_t)e*FFD + fb*32 + srow)*DHID + u8*16;
  const float* Up = uw + ((size_t)e*FFD + fb*32 + srow)*DHID + u8*16;
  int aslot = mc*32 + wm*16 + lr;
  int acl = (aslot<cnt)? aslot : (cnt-1);
  const unsigned short* Ap = hnb + (size_t)toklist[e*TOK+acl]*DHID + lg*8;
  __syncthreads();
  int base = sbase;

  f32x4 ag = {}, au = {};
  f4 G[4], U[4];
  uint4 av[4];

  #define ISSUE_G(s) { _Pragma("unroll") for(int j=0;j<4;j++) G[j] = __builtin_nontemporal_load((const f4*)(Gp + (s)*128 + j*4)); }
  #define ISSUE_U(s) { _Pragma("unroll") for(int j=0;j<4;j++) U[j] = __builtin_nontemporal_load((const f4*)(Up + (s)*128 + j*4)); }
  #define ISSUE_A(s) { _Pragma("unroll") for(int kf=0;kf<4;kf++) av[kf] = *(const uint4*)(Ap + (s)*128 + kf*32); }
  // pack 16 f32 -> 2 x 16B units at swizzled unit (u ^ (row&15))
  #define WRITE_X(BK,DST) { \
    uint4 q0 = make_uint4(pk2(BK[0][0],BK[0][1]),pk2(BK[0][2],BK[0][3]),pk2(BK[1][0],BK[1][1]),pk2(BK[1][2],BK[1][3])); \
    uint4 q1 = make_uint4(pk2(BK[2][0],BK[2][1]),pk2(BK[2][2],BK[2][3]),pk2(BK[3][0],BK[3][1]),pk2(BK[3][2],BK[3][3])); \
    int u0 = (u8*2)   ^ (srow&15); \
    int u1 = (u8*2+1) ^ (srow&15); \
    *(uint4*)&DST[srow*128 + u0*8] = q0; \
    *(uint4*)&DST[srow*128 + u1*8] = q1; }
  #define COMPUTE() { \
    _Pragma("unroll") \
    for(int kf=0;kf<4;kf++){ \
      bf16x8 af = as_bf8(av[kf]); \
      int Rl = wn*16 + lr; \
      int up = (kf*4+lg) ^ lr; \
      bf16x8 gfr = *(const bf16x8*)&Gs[Rl*128 + up*8]; \
      bf16x8 ufr = *(const bf16x8*)&Us[Rl*128 + up*8]; \
      ag = __builtin_amdgcn_mfma_f32_16x16x32_bf16(af, gfr, ag, 0,0,0); \
      au = __builtin_amdgcn_mfma_f32_16x16x32_bf16(af, ufr, au, 0,0,0); \
    } }

  const int NS = DHID/128;  // 16
  ISSUE_G(0) ISSUE_U(0) ISSUE_A(0)
  for(int s=0;s<NS;s++){
    if(s+1<NS){
      WAITV(8)                 // G(s) landed
      WRITE_X(G, Gs)
      ISSUE_G(s+1)
      WAITV(8)                 // U(s) landed
      WRITE_X(U, Us)
      ISSUE_U(s+1)
      WAITL0
      __builtin_amdgcn_s_barrier(); SB
      WAITV(8)                 // A(s) landed; G/U(s+1) stay in flight
      COMPUTE()
      ISSUE_A(s+1)
      __builtin_amdgcn_s_barrier(); SB
    } else {
      WAITV(8)
      WRITE_X(G, Gs)
      WAITV(4)
      WRITE_X(U, Us)
      WAITL0
      __builtin_amdgcn_s_barrier(); SB
      WAITV(0)
      COMPUTE()
      __builtin_amdgcn_s_barrier(); SB
    }
  }
  #undef ISSUE_G
  #undef ISSUE_U
  #undef ISSUE_A
  #undef WRITE_X
  #undef COMPUTE

  {
    int f = fb*32 + wn*16 + lr;
    #pragma unroll
    for(int rg=0;rg<4;rg++){
      int sl = wm*16 + lg*4 + rg;
      int slot = mc*32 + sl;
      if(slot < cnt){
        float cw = wlist[e*TOK + slot];
        float g = ag[rg], u = au[rg];
        float mval = g/(1.0f+expf(-g))*u*cw;
        mid[((size_t)(base+slot))*FFD + f] = f2bf(mval);
      }
    }
  }
}

// ---------------- MoE down v9: r8 structure, 4 blocks/CU ----------------
__global__ __launch_bounds__(256,4) void moe_down_kernel(const unsigned short* __restrict__ mid,
  const float* __restrict__ dwn, const int* __restrict__ counts,
  const int* __restrict__ toklist, float* __restrict__ out)
{
  int nb=blockIdx.x, e=blockIdx.y, mc=blockIdx.z;
  int cnt=counts[e];
  if(mc*32>=cnt) return;
  int tid=threadIdx.x;
  __shared__ int sbase;
  if(tid<64){
    int c = counts[tid];
    int v = c;
    #pragma unroll
    for(int o=1;o<64;o<<=1){ int n=__shfl_up(v,o); if(tid>=o) v+=n; }
    if(tid==e) sbase = v - c;
  }
  __shared__ unsigned short Ds[64*256];   // 32 KB
  int w=tid>>6, lane=tid&63;
  int wm=w>>1, wn=w&1, lr=lane&15, lg=lane>>4;
  int srow=tid>>2, sc4=tid&3, rx=srow&7;
  int halfo=(sc4&1)*4, vbase=sc4>>1;

  const float* Dp = dwn + ((size_t)e*DHID + nb*64 + srow)*FFD + sc4*4;
  __syncthreads();
  int base = sbase;
  int slot0 = mc*32 + wm*16 + lr;
  int sla = (slot0<cnt)? slot0 : (cnt-1);
  const unsigned short* Ap = mid + (size_t)(base+sla)*FFD + lg*8;

  f32x4 acc[2]={};
  f4 P[8], Q[8];
  uint4 av[8];

  #define ISSUE(BK,s,jb) { \
    _Pragma("unroll") \
    for(int j=0;j<8;j++) BK[j] = __builtin_nontemporal_load((const f4*)(Dp + (s)*256 + ((jb)+j)*16)); }
  #define WRITE(BK,jb) { \
    _Pragma("unroll") \
    for(int j=0;j<8;j++){ \
      int v = ((jb)+j)*2 + vbase; \
      int vp = (v & ~7) | ((v&7) ^ rx); \
      uint2 val; val.x = pk2(BK[j][0],BK[j][1]); val.y = pk2(BK[j][2],BK[j][3]); \
      *(uint2*)&Ds[srow*256 + vp*8 + halfo] = val; } }
  #define ISSUE_A(s) { \
    _Pragma("unroll") \
    for(int kf=0;kf<8;kf++) av[kf] = *(const uint4*)(Ap + (s)*256 + kf*32); }
  #define COMPUTE() { \
    _Pragma("unroll") \
    for(int kf=0;kf<8;kf++){ \
      bf16x8 af = as_bf8(av[kf]); \
      _Pragma("unroll") \
      for(int ni=0;ni<2;ni++){ \
        int R = wn*32 + ni*16 + lr; \
        int v = kf*4 + lg; \
        int vp = (v & ~7) | ((v&7) ^ (lr&7)); \
        bf16x8 dfr = *(const bf16x8*)&Ds[R*256 + vp*8]; \
        acc[ni] = __builtin_amdgcn_mfma_f32_16x16x32_bf16(af, dfr, acc[ni], 0,0,0); \
      } \
    } }

  const int NS = FFD/256;  // 4
  ISSUE(P, 0, 0)
  ISSUE(Q, 0, 8)
  for(int s=0;s<NS;s++){
    WAITV(8)
    WRITE(P, 0)
    ISSUE_A(s)
    WAITV(8)
    WRITE(Q, 8)
    if(s+1<NS){ ISSUE(P, s+1, 0) }
    WAITL0
    __builtin_amdgcn_s_barrier(); SB
    if(s+1<NS){ WAITV(8) } else { WAITV(0) }
    COMPUTE()
    if(s+1<NS){ ISSUE(Q, s+1, 8) }
    __builtin_amdgcn_s_barrier(); SB
  }
  #undef ISSUE
  #undef WRITE
  #undef ISSUE_A
  #undef COMPUTE

  #pragma unroll
  for(int ni=0;ni<2;ni++){
    int d = nb*64 + wn*32 + ni*16 + lr;
    #pragma unroll
    for(int rg=0;rg<4;rg++){
      int sl=wm*16+lg*4+rg, slot=mc*32+sl;
      if(slot<cnt){
        int tok = toklist[e*TOK + slot];
        atomicAdd(out + (size_t)tok*DHID + d, acc[ni][rg]);
      }
    }
  }
}

extern "C" void kernel_launch(void* const* d_in, const int* in_sizes, int n_in,
                              void* d_out, int out_size, void* d_ws, size_t ws_size,
                              hipStream_t stream)
{
  (void)in_sizes; (void)n_in; (void)out_size; (void)ws_size;
  const float* x    = (const float*)d_in[0];
  const float* ln1w = (const float*)d_in[1];
  const float* qw   = (const float*)d_in[2];
  const float* kw   = (const float*)d_in[3];
  const float* vw   = (const float*)d_in[4];
  const float* ow   = (const float*)d_in[5];
  const float* qnw  = (const float*)d_in[6];
  const float* knw  = (const float*)d_in[7];
  const float* ln2w = (const float*)d_in[8];
  const float* rw   = (const float*)d_in[9];
  const float* gw   = (const float*)d_in[10];
  const float* uw   = (const float*)d_in[11];
  const float* dwn  = (const float*)d_in[12];
  float* out = (float*)d_out;

  char* p = (char*)d_ws;
  auto alloc = [&](size_t bytes)->void*{ void* r = (void*)p; p += (bytes + 255) & ~(size_t)255; return r; };
  unsigned short* xnb = (unsigned short*)alloc((size_t)TOK*DHID*2);
  float* qf   = (float*)alloc((size_t)TOK*DHID*4);
  float* kf   = (float*)alloc((size_t)TOK*DHID*4);
  float* vf   = (float*)alloc((size_t)TOK*DHID*4);
  float* qh   = (float*)alloc((size_t)TOK*DHID*4);
  float* kh   = (float*)alloc((size_t)TOK*DHID*4);
  float* ctx  = (float*)alloc((size_t)TOK*DHID*4);
  float* hbuf = (float*)alloc((size_t)TOK*DHID*4);
  float* hnf  = (float*)alloc((size_t)TOK*DHID*4);
  unsigned short* hnb = (unsigned short*)alloc((size_t)TOK*DHID*2);
  float* csb  = (float*)alloc((size_t)TOK*64*4);
  float* snb  = (float*)alloc((size_t)TOK*64*4);
  int* counts = (int*)alloc(NEXP*4);
  int* toklist= (int*)alloc((size_t)NEXP*TOK*4);
  float* wlist= (float*)alloc((size_t)NEXP*TOK*4);
  unsigned short* mid = (unsigned short*)alloc((size_t)TOK*KSEL*FFD*2);

  rope_table_kernel<<<64,256,0,stream>>>(csb,snb);
  rms_kernel<<<TOK,256,0,stream>>>(x, ln1w, xnb, nullptr);
  gemm_qkv_kernel<<<dim3(96,4),256,0,stream>>>(xnb,qw,kw,vw,qf,kf,vf);
  qknorm_rope_kernel<<<TOK,256,0,stream>>>(qf,qnw,csb,snb,qh);
  qknorm_rope_kernel<<<TOK,256,0,stream>>>(kf,knw,csb,snb,kh);
  attn_kernel<<<256,256,0,stream>>>(qh,kh,vf,ctx);
  gemm_o_kernel<<<dim3(32,4),256,0,stream>>>(ctx,ow,x,hbuf,out);
  rms_kernel<<<TOK,256,0,stream>>>(hbuf, ln2w, hnb, hnf);
  hipMemsetAsync(counts,0,NEXP*4,stream);
  router_kernel<<<TOK,256,0,stream>>>(hnf,rw,counts,toklist,wlist);
  moe_gateup_kernel<<<dim3(32,NEXP,8),256,0,stream>>>(hnb,gw,uw,counts,toklist,wlist,mid);
  moe_down_kernel<<<dim3(32,NEXP,8),256,0,stream>>>(mid,dwn,counts,toklist,out);
}

// Round 10
// 600.396 us; speedup vs baseline: 1.4455x; 1.4455x over previous
//
#include <hip/hip_runtime.h>
#include <math.h>

#define DHID 2048
#define TOK 256
#define NHEAD 16
#define HDIM 128
#define NEXP 64
#define KSEL 8
#define FFD 1024
#define RMSEPS 1e-5f
#define ATTNSCALE 0.08838834764831845f

typedef short bf16x8 __attribute__((ext_vector_type(8)));
typedef float f32x4 __attribute__((ext_vector_type(4)));
typedef float f4 __attribute__((ext_vector_type(4)));

__device__ __forceinline__ unsigned short f2bf(float f){
  union { float f; unsigned int u; } c; c.f = f;
  unsigned int u = c.u + 0x7fffu + ((c.u>>16)&1u);
  return (unsigned short)(u>>16);
}
__device__ __forceinline__ unsigned int pk2(float a, float b){
  return (unsigned int)f2bf(a) | ((unsigned int)f2bf(b)<<16);
}
__device__ __forceinline__ bf16x8 as_bf8(uint4 u){
  union { uint4 u; bf16x8 v; } c; c.u = u; return c.v;
}

#define WAITV(N) { asm volatile("s_waitcnt vmcnt(" #N ")" ::: "memory"); __builtin_amdgcn_sched_barrier(0); }
#define WAITL0   { asm volatile("s_waitcnt lgkmcnt(0)" ::: "memory"); __builtin_amdgcn_sched_barrier(0); }
#define SB       __builtin_amdgcn_sched_barrier(0);

// ---------------- RMSNorm (bf16 out + optional f32 out) ----------------
__global__ __launch_bounds__(256) void rms_kernel(const float* __restrict__ x,
    const float* __restrict__ w, unsigned short* __restrict__ obf,
    float* __restrict__ of32)
{
  int row = blockIdx.x, tid = threadIdx.x;
  const float* xr = x + (size_t)row*DHID;
  float4 a = *(const float4*)(xr + tid*8);
  float4 b = *(const float4*)(xr + tid*8 + 4);
  float ss = a.x*a.x+a.y*a.y+a.z*a.z+a.w*a.w + b.x*b.x+b.y*b.y+b.z*b.z+b.w*b.w;
  #pragma unroll
  for(int o=32;o>0;o>>=1) ss += __shfl_down(ss,o);
  __shared__ float red[4];
  if((tid&63)==0) red[tid>>6]=ss;
  __syncthreads();
  float r = rsqrtf((red[0]+red[1]+red[2]+red[3])*(1.0f/DHID) + RMSEPS);
  float v[8] = {a.x,a.y,a.z,a.w,b.x,b.y,b.z,b.w};
  unsigned short ob[8];
  #pragma unroll
  for(int j=0;j<8;j++){
    float val = v[j]*r*w[tid*8+j];
    ob[j]=f2bf(val);
    if(of32) of32[(size_t)row*DHID + tid*8 + j] = val;
  }
  uint4 o4;
  o4.x = (unsigned int)ob[0] | ((unsigned int)ob[1]<<16);
  o4.y = (unsigned int)ob[2] | ((unsigned int)ob[3]<<16);
  o4.z = (unsigned int)ob[4] | ((unsigned int)ob[5]<<16);
  o4.w = (unsigned int)ob[6] | ((unsigned int)ob[7]<<16);
  *(uint4*)(obf + (size_t)row*DHID + tid*8) = o4;
}

// ---------------- RoPE cos/sin table [256][64] ----------------
__global__ void rope_table_kernel(float* __restrict__ cs, float* __restrict__ sn){
  int i = blockIdx.x*256 + threadIdx.x;  // 16384
  int s = i>>6, j = i&63;
  float invf = powf(10000.0f, -(float)j*(1.0f/64.0f));
  float ang = (float)s * invf;
  cs[i] = cosf(ang); sn[i] = sinf(ang);
}

// ---------------- fused QKV GEMM: C[s,o] = sum_d xn[s,d]*W[o,d] ----------------
__global__ __launch_bounds__(256) void gemm_qkv_kernel(
    const unsigned short* __restrict__ A,
    const float* __restrict__ qw, const float* __restrict__ kw, const float* __restrict__ vw,
    float* __restrict__ qo, float* __restrict__ ko, float* __restrict__ vo)
{
  int nt = blockIdx.x, mt = blockIdx.y;
  int which = nt>>5, nb = nt&31;
  const float* W = (which==0)? qw : (which==1)? kw : vw;
  float* OUT = (which==0)? qo : (which==1)? ko : vo;
  int n0 = nb*64, m0 = mt*64;
  __shared__ unsigned short As[64*64];
  __shared__ unsigned short Bs[64*64];
  int tid = threadIdx.x;
  int wid = tid>>6, lane = tid&63;
  int wm = wid>>1, wn = wid&1;
  int lr = lane&15, lg = lane>>4;
  int sr = tid>>2, sq = tid&3;
  f32x4 acc[2][2] = {};
  const unsigned short* Ap = A + (size_t)(m0+sr)*DHID + sq*16;
  const float* Bp = W + (size_t)(n0+sr)*DHID + sq*16;
  for(int k0=0;k0<DHID;k0+=64){
    uint4 a0 = *(const uint4*)(Ap + k0);
    uint4 a1 = *(const uint4*)(Ap + k0 + 8);
    float4 b0 = *(const float4*)(Bp + k0);
    float4 b1 = *(const float4*)(Bp + k0 + 4);
    float4 b2 = *(const float4*)(Bp + k0 + 8);
    float4 b3 = *(const float4*)(Bp + k0 + 12);
    int x7 = sr&7;
    *(uint4*)&As[sr*64 + (((sq*2)  ^ x7)*8)] = a0;
    *(uint4*)&As[sr*64 + (((sq*2+1)^ x7)*8)] = a1;
    uint4 p0 = make_uint4(pk2(b0.x,b0.y),pk2(b0.z,b0.w),pk2(b1.x,b1.y),pk2(b1.z,b1.w));
    uint4 p1 = make_uint4(pk2(b2.x,b2.y),pk2(b2.z,b2.w),pk2(b3.x,b3.y),pk2(b3.z,b3.w));
    *(uint4*)&Bs[sr*64 + (((sq*2)  ^ x7)*8)] = p0;
    *(uint4*)&Bs[sr*64 + (((sq*2+1)^ x7)*8)] = p1;
    __syncthreads();
    #pragma unroll
    for(int ki=0;ki<2;ki++){
      bf16x8 af[2], bfr[2];
      #pragma unroll
      for(int mi=0;mi<2;mi++){
        int r = wm*32 + mi*16 + lr;
        af[mi] = *(const bf16x8*)&As[r*64 + (((ki*4+lg)^(r&7))*8)];
      }
      #pragma unroll
      for(int ni=0;ni<2;ni++){
        int r = wn*32 + ni*16 + lr;
        bfr[ni] = *(const bf16x8*)&Bs[r*64 + (((ki*4+lg)^(r&7))*8)];
      }
      #pragma unroll
      for(int mi=0;mi<2;mi++)
        #pragma unroll
        for(int ni=0;ni<2;ni++)
          acc[mi][ni] = __builtin_amdgcn_mfma_f32_16x16x32_bf16(af[mi], bfr[ni], acc[mi][ni], 0,0,0);
    }
    __syncthreads();
  }
  #pragma unroll
  for(int mi=0;mi<2;mi++){
    #pragma unroll
    for(int ni=0;ni<2;ni++){
      int col = n0 + wn*32 + ni*16 + lr;
      int rowb = m0 + wm*32 + mi*16 + lg*4;
      #pragma unroll
      for(int rg=0;rg<4;rg++)
        OUT[(size_t)(rowb+rg)*DHID + col] = acc[mi][ni][rg];
    }
  }
}

// ---------------- O-proj GEMM (A f32->bf16 staged) + residual, dual store ----------------
__global__ __launch_bounds__(256) void gemm_o_kernel(const float* __restrict__ A,
  const float* __restrict__ W, const float* __restrict__ X,
  float* __restrict__ H, float* __restrict__ O)
{
  int nb = blockIdx.x, mt = blockIdx.y;
  int n0 = nb*64, m0 = mt*64;
  __shared__ unsigned short As[64*64];
  __shared__ unsigned short Bs[64*64];
  int tid = threadIdx.x;
  int wid = tid>>6, lane = tid&63;
  int wm = wid>>1, wn = wid&1;
  int lr = lane&15, lg = lane>>4;
  int sr = tid>>2, sq = tid&3;
  f32x4 acc[2][2] = {};
  const float* Ap = A + (size_t)(m0+sr)*DHID + sq*16;
  const float* Bp = W + (size_t)(n0+sr)*DHID + sq*16;
  for(int k0=0;k0<DHID;k0+=64){
    float4 a0=*(const float4*)(Ap+k0),   a1=*(const float4*)(Ap+k0+4);
    float4 a2=*(const float4*)(Ap+k0+8), a3=*(const float4*)(Ap+k0+12);
    float4 b0=*(const float4*)(Bp+k0),   b1=*(const float4*)(Bp+k0+4);
    float4 b2=*(const float4*)(Bp+k0+8), b3=*(const float4*)(Bp+k0+12);
    int x7 = sr&7;
    uint4 pa0 = make_uint4(pk2(a0.x,a0.y),pk2(a0.z,a0.w),pk2(a1.x,a1.y),pk2(a1.z,a1.w));
    uint4 pa1 = make_uint4(pk2(a2.x,a2.y),pk2(a2.z,a2.w),pk2(a3.x,a3.y),pk2(a3.z,a3.w));
    uint4 pb0 = make_uint4(pk2(b0.x,b0.y),pk2(b0.z,b0.w),pk2(b1.x,b1.y),pk2(b1.z,b1.w));
    uint4 pb1 = make_uint4(pk2(b2.x,b2.y),pk2(b2.z,b2.w),pk2(b3.x,b3.y),pk2(b3.z,b3.w));
    *(uint4*)&As[sr*64 + (((sq*2)  ^ x7)*8)] = pa0;
    *(uint4*)&As[sr*64 + (((sq*2+1)^ x7)*8)] = pa1;
    *(uint4*)&Bs[sr*64 + (((sq*2)  ^ x7)*8)] = pb0;
    *(uint4*)&Bs[sr*64 + (((sq*2+1)^ x7)*8)] = pb1;
    __syncthreads();
    #pragma unroll
    for(int ki=0;ki<2;ki++){
      bf16x8 af[2], bfr[2];
      #pragma unroll
      for(int mi=0;mi<2;mi++){
        int r = wm*32 + mi*16 + lr;
        af[mi] = *(const bf16x8*)&As[r*64 + (((ki*4+lg)^(r&7))*8)];
      }
      #pragma unroll
      for(int ni=0;ni<2;ni++){
        int r = wn*32 + ni*16 + lr;
        bfr[ni] = *(const bf16x8*)&Bs[r*64 + (((ki*4+lg)^(r&7))*8)];
      }
      #pragma unroll
      for(int mi=0;mi<2;mi++)
        #pragma unroll
        for(int ni=0;ni<2;ni++)
          acc[mi][ni] = __builtin_amdgcn_mfma_f32_16x16x32_bf16(af[mi], bfr[ni], acc[mi][ni], 0,0,0);
    }
    __syncthreads();
  }
  #pragma unroll
  for(int mi=0;mi<2;mi++){
    #pragma unroll
    for(int ni=0;ni<2;ni++){
      int col = n0 + wn*32 + ni*16 + lr;
      int rowb = m0 + wm*32 + mi*16 + lg*4;
      #pragma unroll
      for(int rg=0;rg<4;rg++){
        size_t idx = (size_t)(rowb+rg)*DHID + col;
        float v = acc[mi][ni][rg] + X[idx];
        H[idx] = v; O[idx] = v;
      }
    }
  }
}

// ---------------- QK RMSNorm (full 2048) + RoPE, f32 out [head][tok][128] ----------------
__global__ __launch_bounds__(256) void qknorm_rope_kernel(const float* __restrict__ in,
   const float* __restrict__ w, const float* __restrict__ cs, const float* __restrict__ sn,
   float* __restrict__ out)
{
  int t = blockIdx.x, tid = threadIdx.x;
  __shared__ float xs[DHID];
  const float* xr = in + (size_t)t*DHID;
  float4 a = *(const float4*)(xr + tid*8);
  float4 b = *(const float4*)(xr + tid*8 + 4);
  *(float4*)&xs[tid*8] = a; *(float4*)&xs[tid*8+4] = b;
  float ss = a.x*a.x+a.y*a.y+a.z*a.z+a.w*a.w + b.x*b.x+b.y*b.y+b.z*b.z+b.w*b.w;
  #pragma unroll
  for(int o=32;o>0;o>>=1) ss += __shfl_down(ss,o);
  __shared__ float red[4];
  if((tid&63)==0) red[tid>>6]=ss;
  __syncthreads();
  float r = rsqrtf((red[0]+red[1]+red[2]+red[3])*(1.0f/DHID) + RMSEPS);
  int hh = tid>>4, jb = (tid&15)*4;
  #pragma unroll
  for(int p=0;p<4;p++){
    int j = jb+p;
    int i0 = hh*HDIM + j, i1 = i0+64;
    float va = xs[i0]*r*w[i0];
    float vb = xs[i1]*r*w[i1];
    float c = cs[t*64+j], s = sn[t*64+j];
    out[((size_t)(hh*TOK + t))*HDIM + j]    = va*c - vb*s;
    out[((size_t)(hh*TOK + t))*HDIM + j+64] = vb*c + va*s;
  }
}

// ---------------- causal attention, f32, 16 q-rows per block (V read from [tok][D] direct) ----------------
__global__ __launch_bounds__(256) void attn_kernel(const float* __restrict__ qh,
  const float* __restrict__ kh, const float* __restrict__ vf, float* __restrict__ ctx)
{
  int head = blockIdx.x>>4, qt = blockIdx.x&15;
  __shared__ float qs[16][132];
  __shared__ float sc[16][260];
  __shared__ float red[16][16];
  __shared__ float rmx[16], rsm[16];
  int tid = threadIdx.x;
  {
    int r = tid>>4, c = (tid&15)*8;
    const float* src = qh + ((size_t)(head*TOK + qt*16 + r))*HDIM + c;
    *(float4*)&qs[r][c]   = *(const float4*)(src);
    *(float4*)&qs[r][c+4] = *(const float4*)(src+4);
  }
  __syncthreads();
  int qi = tid&15, kk = tid>>4;
  int qg = qt*16 + qi;
  for(int k=kk; k<=qg; k+=16){
    const float* kp = kh + ((size_t)(head*TOK + k))*HDIM;
    float d = 0.f;
    #pragma unroll 8
    for(int c=0;c<128;c+=4){
      float4 kv = *(const float4*)(kp + c);
      float4 qv = *(const float4*)&qs[qi][c];
      d += qv.x*kv.x + qv.y*kv.y + qv.z*kv.z + qv.w*kv.w;
    }
    sc[qi][k] = d*ATTNSCALE;
  }
  float m = -1e30f;
  for(int k=kk;k<=qg;k+=16) m = fmaxf(m, sc[qi][k]);
  red[qi][kk] = m;
  __syncthreads();
  if(kk==0){
    float mm=-1e30f;
    #pragma unroll
    for(int j=0;j<16;j++) mm = fmaxf(mm, red[qi][j]);
    rmx[qi]=mm;
  }
  __syncthreads();
  float mm = rmx[qi];
  float s = 0.f;
  for(int k=kk;k<=qg;k+=16){ float pp = expf(sc[qi][k]-mm); sc[qi][k]=pp; s+=pp; }
  red[qi][kk]=s;
  __syncthreads();
  if(kk==0){
    float t_=0.f;
    #pragma unroll
    for(int j=0;j<16;j++) t_ += red[qi][j];
    rsm[qi]=t_;
  }
  __syncthreads();
  int dg = kk;
  float acc[8]={0,0,0,0,0,0,0,0};
  const float* vp = vf + head*HDIM + dg*8;
  for(int k=0;k<=qg;k++){
    float p = sc[qi][k];
    float4 v0 = *(const float4*)(vp + (size_t)k*DHID);
    float4 v1 = *(const float4*)(vp + (size_t)k*DHID + 4);
    acc[0]+=p*v0.x; acc[1]+=p*v0.y; acc[2]+=p*v0.z; acc[3]+=p*v0.w;
    acc[4]+=p*v1.x; acc[5]+=p*v1.y; acc[6]+=p*v1.z; acc[7]+=p*v1.w;
  }
  float inv = 1.0f/rsm[qi];
  float* op = ctx + ((size_t)(qt*16+qi))*DHID + head*HDIM + dg*8;
  *(float4*)(op)   = make_float4(acc[0]*inv, acc[1]*inv, acc[2]*inv, acc[3]*inv);
  *(float4*)(op+4) = make_float4(acc[4]*inv, acc[5]*inv, acc[6]*inv, acc[7]*inv);
}

// ---------------- router: logits, softmax f32, exact top-8, expert lists ----------------
__global__ __launch_bounds__(256) void router_kernel(const float* __restrict__ hn,
    const float* __restrict__ rw, int* __restrict__ counts, int* __restrict__ toklist,
    float* __restrict__ wlist)
{
  int t = blockIdx.x, tid = threadIdx.x;
  __shared__ float xs[DHID];
  __shared__ float part[NEXP*4];
  __shared__ float probs[NEXP];
  *(float4*)&xs[tid*8]   = *(const float4*)(hn + (size_t)t*DHID + tid*8);
  *(float4*)&xs[tid*8+4] = *(const float4*)(hn + (size_t)t*DHID + tid*8+4);
  __syncthreads();
  int e = tid&63, c = tid>>6;
  const float* w = rw + (size_t)e*DHID + c*512;
  const float* xc = xs + c*512;
  float d = 0.f;
  for(int i=0;i<512;i+=4){
    float4 wv = *(const float4*)(w+i);
    d += xc[i]*wv.x + xc[i+1]*wv.y + xc[i+2]*wv.z + xc[i+3]*wv.w;
  }
  part[c*64 + e] = d;
  __syncthreads();
  if(tid<64){
    float logit = part[tid] + part[64+tid] + part[128+tid] + part[192+tid];
    float m = logit;
    #pragma unroll
    for(int o=32;o>0;o>>=1) m = fmaxf(m, __shfl_xor(m,o));
    float p = expf(logit - m);
    float s = p;
    #pragma unroll
    for(int o=32;o>0;o>>=1) s += __shfl_xor(s,o);
    probs[tid] = p/s;
  }
  __syncthreads();
  if(tid==0){
    unsigned long long used = 0ull;
    for(int r=0;r<KSEL;r++){
      float best = -1.f; int bi = 0;
      for(int j=0;j<NEXP;j++){
        if(!((used>>j)&1ull) && probs[j]>best){ best=probs[j]; bi=j; }
      }
      used |= (1ull<<bi);
      int slot = atomicAdd(&counts[bi],1);
      toklist[bi*TOK+slot] = t;
      wlist[bi*TOK+slot] = best;
    }
  }
}

// ---------------- MoE gate+up v10: CONTIGUOUS-INSTRUCTION staging ----------------
// r7 pipeline (BK=256, 64-row tile, rolling 8-load windows, counted vmcnt(8))
// but each load instruction = ONE row's full 1KB slab (64 lanes x 4 f32
// contiguous) -> per-CU request stream is page-sequential. LDS: 16B-unit XOR
// swizzle p(u) = (u&~15)|((u&15)^(row&15)), matched on write and read.
__global__ __launch_bounds__(256,2) void moe_gateup_kernel(const unsigned short* __restrict__ hnb,
  const float* __restrict__ gw, const float* __restrict__ uw,
  const int* __restrict__ counts,
  const int* __restrict__ toklist, const float* __restrict__ wlist,
  unsigned short* __restrict__ mid)
{
  int fb = blockIdx.x, e = blockIdx.y, mc = blockIdx.z;
  int cnt = counts[e];
  if(mc*32 >= cnt) return;
  int tid = threadIdx.x;
  __shared__ int sbase;
  if(tid<64){
    int c = counts[tid];
    int v = c;
    #pragma unroll
    for(int o=1;o<64;o<<=1){ int n=__shfl_up(v,o); if(tid>=o) v+=n; }
    if(tid==e) sbase = v - c;
  }
  __shared__ unsigned short Gs[64*256];   // 32 KB
  __shared__ unsigned short Us[64*256];   // 32 KB
  int w = tid>>6, lane = tid&63;
  int wm = w>>1, wn = w&1, lr = lane&15, lg = lane>>4;

  // staging: wave w owns rows w*16 .. w*16+15; instr (jb+j) = row's 1KB slab,
  // lane l reads floats [l*4, l*4+4) -> fully contiguous per instruction.
  int r0 = w*16;
  const float* Gp = gw + ((size_t)e*FFD + fb*64 + r0)*DHID + lane*4;
  const float* Up = uw + ((size_t)e*FFD + fb*64 + r0)*DHID + lane*4;
  int aslot = mc*32 + wm*16 + lr;
  int acl = (aslot<cnt)? aslot : (cnt-1);
  const unsigned short* Ap = hnb + (size_t)toklist[e*TOK+acl]*DHID + lg*8;
  __syncthreads();
  int base = sbase;

  f32x4 ag[2]={}, au[2]={};
  f4 P[8], Q[8];
  uint4 av[8];

  int wu = lane>>1, wh = (lane&1)*4;   // write unit (of 32 16B units), half (shorts)

  #define ISSUE(BK,SRC,s,jb) { \
    _Pragma("unroll") \
    for(int j=0;j<8;j++) BK[j] = __builtin_nontemporal_load((const f4*)(SRC + (size_t)((jb)+j)*DHID + (s)*256)); }
  #define WRITE(BK,DST,jb) { \
    _Pragma("unroll") \
    for(int j=0;j<8;j++){ \
      int r = r0 + (jb) + j; \
      int p = (wu & ~15) | ((wu&15) ^ (r&15)); \
      uint2 val; val.x = pk2(BK[j][0],BK[j][1]); val.y = pk2(BK[j][2],BK[j][3]); \
      *(uint2*)&DST[r*256 + p*8 + wh] = val; } }
  #define ISSUE_A(s) { \
    _Pragma("unroll") \
    for(int kf=0;kf<8;kf++) av[kf] = *(const uint4*)(Ap + (s)*256 + kf*32); }
  #define COMPUTE() { \
    _Pragma("unroll") \
    for(int kf=0;kf<8;kf++){ \
      bf16x8 af = as_bf8(av[kf]); \
      _Pragma("unroll") \
      for(int ni=0;ni<2;ni++){ \
        int R = wn*32 + ni*16 + lr; \
        int v = kf*4 + lg; \
        int vp = (v & ~15) | ((v&15) ^ (R&15)); \
        int ho = R*256 + vp*8; \
        bf16x8 gfr = *(const bf16x8*)&Gs[ho]; \
        bf16x8 ufr = *(const bf16x8*)&Us[ho]; \
        ag[ni] = __builtin_amdgcn_mfma_f32_16x16x32_bf16(af, gfr, ag[ni], 0,0,0); \
        au[ni] = __builtin_amdgcn_mfma_f32_16x16x32_bf16(af, ufr, au[ni], 0,0,0); \
      } \
    } }

  const int NS = DHID/256;  // 8
  ISSUE(P, Gp, 0, 0)
  ISSUE(Q, Gp, 0, 8)
  for(int s=0;s<NS;s++){
    WAITV(8)                          // G rows 0-7 landed (rows 8-15 in flight)
    WRITE(P, Gs, 0)
    ISSUE(P, Up, s, 0)
    WAITV(8)                          // G rows 8-15 landed
    WRITE(Q, Gs, 8)
    ISSUE(Q, Up, s, 8)
    WAITV(8)                          // U rows 0-7 landed
    WRITE(P, Us, 0)
    ISSUE_A(s)
    WAITV(8)                          // U rows 8-15 landed (A in flight)
    WRITE(Q, Us, 8)
    if(s+1<NS){ ISSUE(P, Gp, s+1, 0) }
    WAITL0
    __builtin_amdgcn_s_barrier(); SB
    if(s+1<NS){ WAITV(8) } else { WAITV(0) }   // A landed; next G stays in flight
    COMPUTE()
    if(s+1<NS){ ISSUE(Q, Gp, s+1, 8) }
    __builtin_amdgcn_s_barrier(); SB
  }
  #undef ISSUE
  #undef WRITE
  #undef ISSUE_A
  #undef COMPUTE

  #pragma unroll
  for(int ni=0;ni<2;ni++){
    int f = fb*64 + wn*32 + ni*16 + lr;
    #pragma unroll
    for(int rg=0;rg<4;rg++){
      int sl = wm*16 + lg*4 + rg;
      int slot = mc*32 + sl;
      if(slot < cnt){
        float cw = wlist[e*TOK + slot];
        float g = ag[ni][rg], u = au[ni][rg];
        float mval = g/(1.0f+expf(-g))*u*cw;
        mid[((size_t)(base+slot))*FFD + f] = f2bf(mval);
      }
    }
  }
}

// ---------------- MoE down v10: contiguous-instruction staging ----------------
__global__ __launch_bounds__(256,3) void moe_down_kernel(const unsigned short* __restrict__ mid,
  const float* __restrict__ dwn, const int* __restrict__ counts,
  const int* __restrict__ toklist, float* __restrict__ out)
{
  int nb=blockIdx.x, e=blockIdx.y, mc=blockIdx.z;
  int cnt=counts[e];
  if(mc*32>=cnt) return;
  int tid=threadIdx.x;
  __shared__ int sbase;
  if(tid<64){
    int c = counts[tid];
    int v = c;
    #pragma unroll
    for(int o=1;o<64;o<<=1){ int n=__shfl_up(v,o); if(tid>=o) v+=n; }
    if(tid==e) sbase = v - c;
  }
  __shared__ unsigned short Ds[64*256];   // 32 KB
  int w=tid>>6, lane=tid&63;
  int wm=w>>1, wn=w&1, lr=lane&15, lg=lane>>4;
  int r0 = w*16;
  const float* Dp = dwn + ((size_t)e*DHID + nb*64 + r0)*FFD + lane*4;
  __syncthreads();
  int base = sbase;
  int slot0 = mc*32 + wm*16 + lr;
  int sla = (slot0<cnt)? slot0 : (cnt-1);
  const unsigned short* Ap = mid + (size_t)(base+sla)*FFD + lg*8;

  f32x4 acc[2]={};
  f4 P[8], Q[8];
  uint4 av[8];
  int wu = lane>>1, wh = (lane&1)*4;

  #define ISSUE(BK,s,jb) { \
    _Pragma("unroll") \
    for(int j=0;j<8;j++) BK[j] = __builtin_nontemporal_load((const f4*)(Dp + (size_t)((jb)+j)*FFD + (s)*256)); }
  #define WRITE(BK,jb) { \
    _Pragma("unroll") \
    for(int j=0;j<8;j++){ \
      int r = r0 + (jb) + j; \
      int p = (wu & ~15) | ((wu&15) ^ (r&15)); \
      uint2 val; val.x = pk2(BK[j][0],BK[j][1]); val.y = pk2(BK[j][2],BK[j][3]); \
      *(uint2*)&Ds[r*256 + p*8 + wh] = val; } }
  #define ISSUE_A(s) { \
    _Pragma("unroll") \
    for(int kf=0;kf<8;kf++) av[kf] = *(const uint4*)(Ap + (s)*256 + kf*32); }
  #define COMPUTE() { \
    _Pragma("unroll") \
    for(int kf=0;kf<8;kf++){ \
      bf16x8 af = as_bf8(av[kf]); \
      _Pragma("unroll") \
      for(int ni=0;ni<2;ni++){ \
        int R = wn*32 + ni*16 + lr; \
        int v = kf*4 + lg; \
        int vp = (v & ~15) | ((v&15) ^ (R&15)); \
        bf16x8 dfr = *(const bf16x8*)&Ds[R*256 + vp*8]; \
        acc[ni] = __builtin_amdgcn_mfma_f32_16x16x32_bf16(af, dfr, acc[ni], 0,0,0); \
      } \
    } }

  const int NS = FFD/256;  // 4
  ISSUE(P, 0, 0)
  ISSUE(Q, 0, 8)
  for(int s=0;s<NS;s++){
    WAITV(8)
    WRITE(P, 0)
    ISSUE_A(s)
    WAITV(8)
    WRITE(Q, 8)
    if(s+1<NS){ ISSUE(P, s+1, 0) }
    WAITL0
    __builtin_amdgcn_s_barrier(); SB
    if(s+1<NS){ WAITV(8) } else { WAITV(0) }
    COMPUTE()
    if(s+1<NS){ ISSUE(Q, s+1, 8) }
    __builtin_amdgcn_s_barrier(); SB
  }
  #undef ISSUE
  #undef WRITE
  #undef ISSUE_A
  #undef COMPUTE

  #pragma unroll
  for(int ni=0;ni<2;ni++){
    int d = nb*64 + wn*32 + ni*16 + lr;
    #pragma unroll
    for(int rg=0;rg<4;rg++){
      int sl=wm*16+lg*4+rg, slot=mc*32+sl;
      if(slot<cnt){
        int tok = toklist[e*TOK + slot];
        atomicAdd(out + (size_t)tok*DHID + d, acc[ni][rg]);
      }
    }
  }
}

extern "C" void kernel_launch(void* const* d_in, const int* in_sizes, int n_in,
                              void* d_out, int out_size, void* d_ws, size_t ws_size,
                              hipStream_t stream)
{
  (void)in_sizes; (void)n_in; (void)out_size; (void)ws_size;
  const float* x    = (const float*)d_in[0];
  const float* ln1w = (const float*)d_in[1];
  const float* qw   = (const float*)d_in[2];
  const float* kw   = (const float*)d_in[3];
  const float* vw   = (const float*)d_in[4];
  const float* ow   = (const float*)d_in[5];
  const float* qnw  = (const float*)d_in[6];
  const float* knw  = (const float*)d_in[7];
  const float* ln2w = (const float*)d_in[8];
  const float* rw   = (const float*)d_in[9];
  const float* gw   = (const float*)d_in[10];
  const float* uw   = (const float*)d_in[11];
  const float* dwn  = (const float*)d_in[12];
  float* out = (float*)d_out;

  char* p = (char*)d_ws;
  auto alloc = [&](size_t bytes)->void*{ void* r = (void*)p; p += (bytes + 255) & ~(size_t)255; return r; };
  unsigned short* xnb = (unsigned short*)alloc((size_t)TOK*DHID*2);
  float* qf   = (float*)alloc((size_t)TOK*DHID*4);
  float* kf   = (float*)alloc((size_t)TOK*DHID*4);
  float* vf   = (float*)alloc((size_t)TOK*DHID*4);
  float* qh   = (float*)alloc((size_t)TOK*DHID*4);
  float* kh   = (float*)alloc((size_t)TOK*DHID*4);
  float* ctx  = (float*)alloc((size_t)TOK*DHID*4);
  float* hbuf = (float*)alloc((size_t)TOK*DHID*4);
  float* hnf  = (float*)alloc((size_t)TOK*DHID*4);
  unsigned short* hnb = (unsigned short*)alloc((size_t)TOK*DHID*2);
  float* csb  = (float*)alloc((size_t)TOK*64*4);
  float* snb  = (float*)alloc((size_t)TOK*64*4);
  int* counts = (int*)alloc(NEXP*4);
  int* toklist= (int*)alloc((size_t)NEXP*TOK*4);
  float* wlist= (float*)alloc((size_t)NEXP*TOK*4);
  unsigned short* mid = (unsigned short*)alloc((size_t)TOK*KSEL*FFD*2);

  rope_table_kernel<<<64,256,0,stream>>>(csb,snb);
  rms_kernel<<<TOK,256,0,stream>>>(x, ln1w, xnb, nullptr);
  gemm_qkv_kernel<<<dim3(96,4),256,0,stream>>>(xnb,qw,kw,vw,qf,kf,vf);
  qknorm_rope_kernel<<<TOK,256,0,stream>>>(qf,qnw,csb,snb,qh);
  qknorm_rope_kernel<<<TOK,256,0,stream>>>(kf,knw,csb,snb,kh);
  attn_kernel<<<256,256,0,stream>>>(qh,kh,vf,ctx);
  gemm_o_kernel<<<dim3(32,4),256,0,stream>>>(ctx,ow,x,hbuf,out);
  rms_kernel<<<TOK,256,0,stream>>>(hbuf, ln2w, hnb, hnf);
  hipMemsetAsync(counts,0,NEXP*4,stream);
  router_kernel<<<TOK,256,0,stream>>>(hnf,rw,counts,toklist,wlist);
  moe_gateup_kernel<<<dim3(16,NEXP,8),256,0,stream>>>(hnb,gw,uw,counts,toklist,wlist,mid);
  moe_down_kernel<<<dim3(32,NEXP,8),256,0,stream>>>(mid,dwn,counts,toklist,out);
}

// Round 11
// 584.577 us; speedup vs baseline: 1.4846x; 1.0271x over previous
//
#include <hip/hip_runtime.h>
#include <math.h>

#define DHID 2048
#define TOK 256
#define NHEAD 16
#define HDIM 128
#define NEXP 64
#define KSEL 8
#define FFD 1024
#define RMSEPS 1e-5f
#define ATTNSCALE 0.08838834764831845f

typedef short bf16x8 __attribute__((ext_vector_type(8)));
typedef float f32x4 __attribute__((ext_vector_type(4)));
typedef float f4 __attribute__((ext_vector_type(4)));

__device__ __forceinline__ unsigned short f2bf(float f){
  union { float f; unsigned int u; } c; c.f = f;
  unsigned int u = c.u + 0x7fffu + ((c.u>>16)&1u);
  return (unsigned short)(u>>16);
}
__device__ __forceinline__ unsigned int pk2(float a, float b){
  return (unsigned int)f2bf(a) | ((unsigned int)f2bf(b)<<16);
}
__device__ __forceinline__ bf16x8 as_bf8(uint4 u){
  union { uint4 u; bf16x8 v; } c; c.u = u; return c.v;
}

#define WAITV(N) { asm volatile("s_waitcnt vmcnt(" #N ")" ::: "memory"); __builtin_amdgcn_sched_barrier(0); }
#define WAITL0   { asm volatile("s_waitcnt lgkmcnt(0)" ::: "memory"); __builtin_amdgcn_sched_barrier(0); }
#define SB       __builtin_amdgcn_sched_barrier(0);

// ---------------- RMSNorm (bf16 out + optional f32 out) ----------------
__global__ __launch_bounds__(256) void rms_kernel(const float* __restrict__ x,
    const float* __restrict__ w, unsigned short* __restrict__ obf,
    float* __restrict__ of32)
{
  int row = blockIdx.x, tid = threadIdx.x;
  const float* xr = x + (size_t)row*DHID;
  float4 a = *(const float4*)(xr + tid*8);
  float4 b = *(const float4*)(xr + tid*8 + 4);
  float ss = a.x*a.x+a.y*a.y+a.z*a.z+a.w*a.w + b.x*b.x+b.y*b.y+b.z*b.z+b.w*b.w;
  #pragma unroll
  for(int o=32;o>0;o>>=1) ss += __shfl_down(ss,o);
  __shared__ float red[4];
  if((tid&63)==0) red[tid>>6]=ss;
  __syncthreads();
  float r = rsqrtf((red[0]+red[1]+red[2]+red[3])*(1.0f/DHID) + RMSEPS);
  float v[8] = {a.x,a.y,a.z,a.w,b.x,b.y,b.z,b.w};
  unsigned short ob[8];
  #pragma unroll
  for(int j=0;j<8;j++){
    float val = v[j]*r*w[tid*8+j];
    ob[j]=f2bf(val);
    if(of32) of32[(size_t)row*DHID + tid*8 + j] = val;
  }
  uint4 o4;
  o4.x = (unsigned int)ob[0] | ((unsigned int)ob[1]<<16);
  o4.y = (unsigned int)ob[2] | ((unsigned int)ob[3]<<16);
  o4.z = (unsigned int)ob[4] | ((unsigned int)ob[5]<<16);
  o4.w = (unsigned int)ob[6] | ((unsigned int)ob[7]<<16);
  *(uint4*)(obf + (size_t)row*DHID + tid*8) = o4;
}

// ---------------- RoPE cos/sin table [256][64] ----------------
__global__ void rope_table_kernel(float* __restrict__ cs, float* __restrict__ sn){
  int i = blockIdx.x*256 + threadIdx.x;  // 16384
  int s = i>>6, j = i&63;
  float invf = powf(10000.0f, -(float)j*(1.0f/64.0f));
  float ang = (float)s * invf;
  cs[i] = cosf(ang); sn[i] = sinf(ang);
}

// ---------------- fused QKV GEMM: C[s,o] = sum_d xn[s,d]*W[o,d] ----------------
__global__ __launch_bounds__(256) void gemm_qkv_kernel(
    const unsigned short* __restrict__ A,
    const float* __restrict__ qw, const float* __restrict__ kw, const float* __restrict__ vw,
    float* __restrict__ qo, float* __restrict__ ko, float* __restrict__ vo)
{
  int nt = blockIdx.x, mt = blockIdx.y;
  int which = nt>>5, nb = nt&31;
  const float* W = (which==0)? qw : (which==1)? kw : vw;
  float* OUT = (which==0)? qo : (which==1)? ko : vo;
  int n0 = nb*64, m0 = mt*64;
  __shared__ unsigned short As[64*64];
  __shared__ unsigned short Bs[64*64];
  int tid = threadIdx.x;
  int wid = tid>>6, lane = tid&63;
  int wm = wid>>1, wn = wid&1;
  int lr = lane&15, lg = lane>>4;
  int sr = tid>>2, sq = tid&3;
  f32x4 acc[2][2] = {};
  const unsigned short* Ap = A + (size_t)(m0+sr)*DHID + sq*16;
  const float* Bp = W + (size_t)(n0+sr)*DHID + sq*16;
  for(int k0=0;k0<DHID;k0+=64){
    uint4 a0 = *(const uint4*)(Ap + k0);
    uint4 a1 = *(const uint4*)(Ap + k0 + 8);
    float4 b0 = *(const float4*)(Bp + k0);
    float4 b1 = *(const float4*)(Bp + k0 + 4);
    float4 b2 = *(const float4*)(Bp + k0 + 8);
    float4 b3 = *(const float4*)(Bp + k0 + 12);
    int x7 = sr&7;
    *(uint4*)&As[sr*64 + (((sq*2)  ^ x7)*8)] = a0;
    *(uint4*)&As[sr*64 + (((sq*2+1)^ x7)*8)] = a1;
    uint4 p0 = make_uint4(pk2(b0.x,b0.y),pk2(b0.z,b0.w),pk2(b1.x,b1.y),pk2(b1.z,b1.w));
    uint4 p1 = make_uint4(pk2(b2.x,b2.y),pk2(b2.z,b2.w),pk2(b3.x,b3.y),pk2(b3.z,b3.w));
    *(uint4*)&Bs[sr*64 + (((sq*2)  ^ x7)*8)] = p0;
    *(uint4*)&Bs[sr*64 + (((sq*2+1)^ x7)*8)] = p1;
    __syncthreads();
    #pragma unroll
    for(int ki=0;ki<2;ki++){
      bf16x8 af[2], bfr[2];
      #pragma unroll
      for(int mi=0;mi<2;mi++){
        int r = wm*32 + mi*16 + lr;
        af[mi] = *(const bf16x8*)&As[r*64 + (((ki*4+lg)^(r&7))*8)];
      }
      #pragma unroll
      for(int ni=0;ni<2;ni++){
        int r = wn*32 + ni*16 + lr;
        bfr[ni] = *(const bf16x8*)&Bs[r*64 + (((ki*4+lg)^(r&7))*8)];
      }
      #pragma unroll
      for(int mi=0;mi<2;mi++)
        #pragma unroll
        for(int ni=0;ni<2;ni++)
          acc[mi][ni] = __builtin_amdgcn_mfma_f32_16x16x32_bf16(af[mi], bfr[ni], acc[mi][ni], 0,0,0);
    }
    __syncthreads();
  }
  #pragma unroll
  for(int mi=0;mi<2;mi++){
    #pragma unroll
    for(int ni=0;ni<2;ni++){
      int col = n0 + wn*32 + ni*16 + lr;
      int rowb = m0 + wm*32 + mi*16 + lg*4;
      #pragma unroll
      for(int rg=0;rg<4;rg++)
        OUT[(size_t)(rowb+rg)*DHID + col] = acc[mi][ni][rg];
    }
  }
}

// ---------------- O-proj GEMM (A f32->bf16 staged) + residual, dual store ----------------
__global__ __launch_bounds__(256) void gemm_o_kernel(const float* __restrict__ A,
  const float* __restrict__ W, const float* __restrict__ X,
  float* __restrict__ H, float* __restrict__ O)
{
  int nb = blockIdx.x, mt = blockIdx.y;
  int n0 = nb*64, m0 = mt*64;
  __shared__ unsigned short As[64*64];
  __shared__ unsigned short Bs[64*64];
  int tid = threadIdx.x;
  int wid = tid>>6, lane = tid&63;
  int wm = wid>>1, wn = wid&1;
  int lr = lane&15, lg = lane>>4;
  int sr = tid>>2, sq = tid&3;
  f32x4 acc[2][2] = {};
  const float* Ap = A + (size_t)(m0+sr)*DHID + sq*16;
  const float* Bp = W + (size_t)(n0+sr)*DHID + sq*16;
  for(int k0=0;k0<DHID;k0+=64){
    float4 a0=*(const float4*)(Ap+k0),   a1=*(const float4*)(Ap+k0+4);
    float4 a2=*(const float4*)(Ap+k0+8), a3=*(const float4*)(Ap+k0+12);
    float4 b0=*(const float4*)(Bp+k0),   b1=*(const float4*)(Bp+k0+4);
    float4 b2=*(const float4*)(Bp+k0+8), b3=*(const float4*)(Bp+k0+12);
    int x7 = sr&7;
    uint4 pa0 = make_uint4(pk2(a0.x,a0.y),pk2(a0.z,a0.w),pk2(a1.x,a1.y),pk2(a1.z,a1.w));
    uint4 pa1 = make_uint4(pk2(a2.x,a2.y),pk2(a2.z,a2.w),pk2(a3.x,a3.y),pk2(a3.z,a3.w));
    uint4 pb0 = make_uint4(pk2(b0.x,b0.y),pk2(b0.z,b0.w),pk2(b1.x,b1.y),pk2(b1.z,b1.w));
    uint4 pb1 = make_uint4(pk2(b2.x,b2.y),pk2(b2.z,b2.w),pk2(b3.x,b3.y),pk2(b3.z,b3.w));
    *(uint4*)&As[sr*64 + (((sq*2)  ^ x7)*8)] = pa0;
    *(uint4*)&As[sr*64 + (((sq*2+1)^ x7)*8)] = pa1;
    *(uint4*)&Bs[sr*64 + (((sq*2)  ^ x7)*8)] = pb0;
    *(uint4*)&Bs[sr*64 + (((sq*2+1)^ x7)*8)] = pb1;
    __syncthreads();
    #pragma unroll
    for(int ki=0;ki<2;ki++){
      bf16x8 af[2], bfr[2];
      #pragma unroll
      for(int mi=0;mi<2;mi++){
        int r = wm*32 + mi*16 + lr;
        af[mi] = *(const bf16x8*)&As[r*64 + (((ki*4+lg)^(r&7))*8)];
      }
      #pragma unroll
      for(int ni=0;ni<2;ni++){
        int r = wn*32 + ni*16 + lr;
        bfr[ni] = *(const bf16x8*)&Bs[r*64 + (((ki*4+lg)^(r&7))*8)];
      }
      #pragma unroll
      for(int mi=0;mi<2;mi++)
        #pragma unroll
        for(int ni=0;ni<2;ni++)
          acc[mi][ni] = __builtin_amdgcn_mfma_f32_16x16x32_bf16(af[mi], bfr[ni], acc[mi][ni], 0,0,0);
    }
    __syncthreads();
  }
  #pragma unroll
  for(int mi=0;mi<2;mi++){
    #pragma unroll
    for(int ni=0;ni<2;ni++){
      int col = n0 + wn*32 + ni*16 + lr;
      int rowb = m0 + wm*32 + mi*16 + lg*4;
      #pragma unroll
      for(int rg=0;rg<4;rg++){
        size_t idx = (size_t)(rowb+rg)*DHID + col;
        float v = acc[mi][ni][rg] + X[idx];
        H[idx] = v; O[idx] = v;
      }
    }
  }
}

// ---------------- QK RMSNorm (full 2048) + RoPE, f32 out [head][tok][128] ----------------
__global__ __launch_bounds__(256) void qknorm_rope_kernel(const float* __restrict__ in,
   const float* __restrict__ w, const float* __restrict__ cs, const float* __restrict__ sn,
   float* __restrict__ out)
{
  int t = blockIdx.x, tid = threadIdx.x;
  __shared__ float xs[DHID];
  const float* xr = in + (size_t)t*DHID;
  float4 a = *(const float4*)(xr + tid*8);
  float4 b = *(const float4*)(xr + tid*8 + 4);
  *(float4*)&xs[tid*8] = a; *(float4*)&xs[tid*8+4] = b;
  float ss = a.x*a.x+a.y*a.y+a.z*a.z+a.w*a.w + b.x*b.x+b.y*b.y+b.z*b.z+b.w*b.w;
  #pragma unroll
  for(int o=32;o>0;o>>=1) ss += __shfl_down(ss,o);
  __shared__ float red[4];
  if((tid&63)==0) red[tid>>6]=ss;
  __syncthreads();
  float r = rsqrtf((red[0]+red[1]+red[2]+red[3])*(1.0f/DHID) + RMSEPS);
  int hh = tid>>4, jb = (tid&15)*4;
  #pragma unroll
  for(int p=0;p<4;p++){
    int j = jb+p;
    int i0 = hh*HDIM + j, i1 = i0+64;
    float va = xs[i0]*r*w[i0];
    float vb = xs[i1]*r*w[i1];
    float c = cs[t*64+j], s = sn[t*64+j];
    out[((size_t)(hh*TOK + t))*HDIM + j]    = va*c - vb*s;
    out[((size_t)(hh*TOK + t))*HDIM + j+64] = vb*c + va*s;
  }
}

// ---------------- causal attention, f32, 16 q-rows per block (V read from [tok][D] direct) ----------------
__global__ __launch_bounds__(256) void attn_kernel(const float* __restrict__ qh,
  const float* __restrict__ kh, const float* __restrict__ vf, float* __restrict__ ctx)
{
  int head = blockIdx.x>>4, qt = blockIdx.x&15;
  __shared__ float qs[16][132];
  __shared__ float sc[16][260];
  __shared__ float red[16][16];
  __shared__ float rmx[16], rsm[16];
  int tid = threadIdx.x;
  {
    int r = tid>>4, c = (tid&15)*8;
    const float* src = qh + ((size_t)(head*TOK + qt*16 + r))*HDIM + c;
    *(float4*)&qs[r][c]   = *(const float4*)(src);
    *(float4*)&qs[r][c+4] = *(const float4*)(src+4);
  }
  __syncthreads();
  int qi = tid&15, kk = tid>>4;
  int qg = qt*16 + qi;
  for(int k=kk; k<=qg; k+=16){
    const float* kp = kh + ((size_t)(head*TOK + k))*HDIM;
    float d = 0.f;
    #pragma unroll 8
    for(int c=0;c<128;c+=4){
      float4 kv = *(const float4*)(kp + c);
      float4 qv = *(const float4*)&qs[qi][c];
      d += qv.x*kv.x + qv.y*kv.y + qv.z*kv.z + qv.w*kv.w;
    }
    sc[qi][k] = d*ATTNSCALE;
  }
  float m = -1e30f;
  for(int k=kk;k<=qg;k+=16) m = fmaxf(m, sc[qi][k]);
  red[qi][kk] = m;
  __syncthreads();
  if(kk==0){
    float mm=-1e30f;
    #pragma unroll
    for(int j=0;j<16;j++) mm = fmaxf(mm, red[qi][j]);
    rmx[qi]=mm;
  }
  __syncthreads();
  float mm = rmx[qi];
  float s = 0.f;
  for(int k=kk;k<=qg;k+=16){ float pp = expf(sc[qi][k]-mm); sc[qi][k]=pp; s+=pp; }
  red[qi][kk]=s;
  __syncthreads();
  if(kk==0){
    float t_=0.f;
    #pragma unroll
    for(int j=0;j<16;j++) t_ += red[qi][j];
    rsm[qi]=t_;
  }
  __syncthreads();
  int dg = kk;
  float acc[8]={0,0,0,0,0,0,0,0};
  const float* vp = vf + head*HDIM + dg*8;
  for(int k=0;k<=qg;k++){
    float p = sc[qi][k];
    float4 v0 = *(const float4*)(vp + (size_t)k*DHID);
    float4 v1 = *(const float4*)(vp + (size_t)k*DHID + 4);
    acc[0]+=p*v0.x; acc[1]+=p*v0.y; acc[2]+=p*v0.z; acc[3]+=p*v0.w;
    acc[4]+=p*v1.x; acc[5]+=p*v1.y; acc[6]+=p*v1.z; acc[7]+=p*v1.w;
  }
  float inv = 1.0f/rsm[qi];
  float* op = ctx + ((size_t)(qt*16+qi))*DHID + head*HDIM + dg*8;
  *(float4*)(op)   = make_float4(acc[0]*inv, acc[1]*inv, acc[2]*inv, acc[3]*inv);
  *(float4*)(op+4) = make_float4(acc[4]*inv, acc[5]*inv, acc[6]*inv, acc[7]*inv);
}

// ---------------- router: logits, softmax f32, exact top-8, expert lists ----------------
__global__ __launch_bounds__(256) void router_kernel(const float* __restrict__ hn,
    const float* __restrict__ rw, int* __restrict__ counts, int* __restrict__ toklist,
    float* __restrict__ wlist)
{
  int t = blockIdx.x, tid = threadIdx.x;
  __shared__ float xs[DHID];
  __shared__ float part[NEXP*4];
  __shared__ float probs[NEXP];
  *(float4*)&xs[tid*8]   = *(const float4*)(hn + (size_t)t*DHID + tid*8);
  *(float4*)&xs[tid*8+4] = *(const float4*)(hn + (size_t)t*DHID + tid*8+4);
  __syncthreads();
  int e = tid&63, c = tid>>6;
  const float* w = rw + (size_t)e*DHID + c*512;
  const float* xc = xs + c*512;
  float d = 0.f;
  for(int i=0;i<512;i+=4){
    float4 wv = *(const float4*)(w+i);
    d += xc[i]*wv.x + xc[i+1]*wv.y + xc[i+2]*wv.z + xc[i+3]*wv.w;
  }
  part[c*64 + e] = d;
  __syncthreads();
  if(tid<64){
    float logit = part[tid] + part[64+tid] + part[128+tid] + part[192+tid];
    float m = logit;
    #pragma unroll
    for(int o=32;o>0;o>>=1) m = fmaxf(m, __shfl_xor(m,o));
    float p = expf(logit - m);
    float s = p;
    #pragma unroll
    for(int o=32;o>0;o>>=1) s += __shfl_xor(s,o);
    probs[tid] = p/s;
  }
  __syncthreads();
  if(tid==0){
    unsigned long long used = 0ull;
    for(int r=0;r<KSEL;r++){
      float best = -1.f; int bi = 0;
      for(int j=0;j<NEXP;j++){
        if(!((used>>j)&1ull) && probs[j]>best){ best=probs[j]; bi=j; }
      }
      used |= (1ull<<bi);
      int slot = atomicAdd(&counts[bi],1);
      toklist[bi*TOK+slot] = t;
      wlist[bi*TOK+slot] = best;
    }
  }
}

// ---------------- MoE gate+up v11: M=128/block (mc=2) -> kill the 8x L2-fill amplification ----------------
// r10 contiguous-instruction weight staging + counted vmcnt; A-operand loads
// (L2-hit bf16) moved into COMPUTE per M-frag. Weights now read only 2x ->
// L2 traffic ~2.1 GB/pass (was 8.5 GB, saturating the ~29 TB/s L2 interface).
__global__ __launch_bounds__(256,2) void moe_gateup_kernel(const unsigned short* __restrict__ hnb,
  const float* __restrict__ gw, const float* __restrict__ uw,
  const int* __restrict__ counts,
  const int* __restrict__ toklist, const float* __restrict__ wlist,
  unsigned short* __restrict__ mid)
{
  int fb = blockIdx.x, e = blockIdx.y, mc = blockIdx.z;
  int cnt = counts[e];
  if(mc*128 >= cnt) return;
  int tid = threadIdx.x;
  __shared__ int sbase;
  if(tid<64){
    int c = counts[tid];
    int v = c;
    #pragma unroll
    for(int o=1;o<64;o<<=1){ int n=__shfl_up(v,o); if(tid>=o) v+=n; }
    if(tid==e) sbase = v - c;
  }
  __shared__ unsigned short Gs[64*256];   // 32 KB
  __shared__ unsigned short Us[64*256];   // 32 KB
  int w = tid>>6, lane = tid&63;
  int wm = w>>1, wn = w&1, lr = lane&15, lg = lane>>4;
  int mbase = mc*128 + wm*64;             // wave's 64-slot chunk (4 frags of 16)

  int r0 = w*16;
  const float* Gp = gw + ((size_t)e*FFD + fb*64 + r0)*DHID + lane*4;
  const float* Up = uw + ((size_t)e*FFD + fb*64 + r0)*DHID + lane*4;
  const unsigned short* Ap[4];
  #pragma unroll
  for(int mi=0;mi<4;mi++){
    int slot = mbase + mi*16 + lr;
    int acl = (slot<cnt)? slot : (cnt-1);
    Ap[mi] = hnb + (size_t)toklist[e*TOK+acl]*DHID + lg*8;
  }
  __syncthreads();
  int base = sbase;

  f32x4 ag[4][2]={}, au[4][2]={};
  f4 P[8], Q[8];
  int wu = lane>>1, wh = (lane&1)*4;

  #define ISSUE(BK,SRC,s,jb) { \
    _Pragma("unroll") \
    for(int j=0;j<8;j++) BK[j] = __builtin_nontemporal_load((const f4*)(SRC + (size_t)((jb)+j)*DHID + (s)*256)); }
  #define WRITE(BK,DST,jb) { \
    _Pragma("unroll") \
    for(int j=0;j<8;j++){ \
      int r = r0 + (jb) + j; \
      int p = (wu & ~15) | ((wu&15) ^ (r&15)); \
      uint2 val; val.x = pk2(BK[j][0],BK[j][1]); val.y = pk2(BK[j][2],BK[j][3]); \
      *(uint2*)&DST[r*256 + p*8 + wh] = val; } }
  #define COMPUTE(s) { \
    _Pragma("unroll") \
    for(int mi=0;mi<4;mi++){ \
      if(mbase + mi*16 < cnt){ \
        uint4 av[8]; \
        _Pragma("unroll") \
        for(int kf=0;kf<8;kf++) av[kf] = *(const uint4*)(Ap[mi] + (size_t)(s)*256 + kf*32); \
        _Pragma("unroll") \
        for(int kf=0;kf<8;kf++){ \
          bf16x8 af = as_bf8(av[kf]); \
          _Pragma("unroll") \
          for(int ni=0;ni<2;ni++){ \
            int R = wn*32 + ni*16 + lr; \
            int v = kf*4 + lg; \
            int vp = (v & ~15) | ((v&15) ^ (R&15)); \
            int ho = R*256 + vp*8; \
            bf16x8 gfr = *(const bf16x8*)&Gs[ho]; \
            bf16x8 ufr = *(const bf16x8*)&Us[ho]; \
            ag[mi][ni] = __builtin_amdgcn_mfma_f32_16x16x32_bf16(af, gfr, ag[mi][ni], 0,0,0); \
            au[mi][ni] = __builtin_amdgcn_mfma_f32_16x16x32_bf16(af, ufr, au[mi][ni], 0,0,0); \
          } \
        } \
      } \
    } }

  const int NS = DHID/256;  // 8
  ISSUE(P, Gp, 0, 0)
  ISSUE(Q, Gp, 0, 8)
  for(int s=0;s<NS;s++){
    WAITV(8)
    WRITE(P, Gs, 0)
    ISSUE(P, Up, s, 0)
    WAITV(8)
    WRITE(Q, Gs, 8)
    ISSUE(Q, Up, s, 8)
    WAITV(8)
    WRITE(P, Us, 0)
    if(s+1<NS){ ISSUE(P, Gp, s+1, 0) }
    if(s+1<NS){ WAITV(8) } else { WAITV(0) }
    WRITE(Q, Us, 8)
    if(s+1<NS){ ISSUE(Q, Gp, s+1, 8) }
    WAITL0
    __builtin_amdgcn_s_barrier(); SB
    COMPUTE(s)
    __builtin_amdgcn_s_barrier(); SB
  }
  #undef ISSUE
  #undef WRITE
  #undef COMPUTE

  #pragma unroll
  for(int mi=0;mi<4;mi++){
    #pragma unroll
    for(int ni=0;ni<2;ni++){
      int f = fb*64 + wn*32 + ni*16 + lr;
      #pragma unroll
      for(int rg=0;rg<4;rg++){
        int slot = mbase + mi*16 + lg*4 + rg;
        if(slot < cnt){
          float cw = wlist[e*TOK + slot];
          float g = ag[mi][ni][rg], u = au[mi][ni][rg];
          float mval = g/(1.0f+expf(-g))*u*cw;
          mid[((size_t)(base+slot))*FFD + f] = f2bf(mval);
        }
      }
    }
  }
}

// ---------------- MoE down v11: M=128/block (mc=2), same discipline ----------------
__global__ __launch_bounds__(256,4) void moe_down_kernel(const unsigned short* __restrict__ mid,
  const float* __restrict__ dwn, const int* __restrict__ counts,
  const int* __restrict__ toklist, float* __restrict__ out)
{
  int nb=blockIdx.x, e=blockIdx.y, mc=blockIdx.z;
  int cnt=counts[e];
  if(mc*128>=cnt) return;
  int tid=threadIdx.x;
  __shared__ int sbase;
  if(tid<64){
    int c = counts[tid];
    int v = c;
    #pragma unroll
    for(int o=1;o<64;o<<=1){ int n=__shfl_up(v,o); if(tid>=o) v+=n; }
    if(tid==e) sbase = v - c;
  }
  __shared__ unsigned short Ds[64*256];   // 32 KB
  int w=tid>>6, lane=tid&63;
  int wm=w>>1, wn=w&1, lr=lane&15, lg=lane>>4;
  int mbase = mc*128 + wm*64;
  int r0 = w*16;
  const float* Dp = dwn + ((size_t)e*DHID + nb*64 + r0)*FFD + lane*4;
  __syncthreads();
  int base = sbase;
  const unsigned short* Ap[4];
  #pragma unroll
  for(int mi=0;mi<4;mi++){
    int slot = mbase + mi*16 + lr;
    int acl = (slot<cnt)? slot : (cnt-1);
    Ap[mi] = mid + (size_t)(base+acl)*FFD + lg*8;
  }

  f32x4 acc[4][2]={};
  f4 P[8], Q[8];
  int wu = lane>>1, wh = (lane&1)*4;

  #define ISSUE(BK,s,jb) { \
    _Pragma("unroll") \
    for(int j=0;j<8;j++) BK[j] = __builtin_nontemporal_load((const f4*)(Dp + (size_t)((jb)+j)*FFD + (s)*256)); }
  #define WRITE(BK,jb) { \
    _Pragma("unroll") \
    for(int j=0;j<8;j++){ \
      int r = r0 + (jb) + j; \
      int p = (wu & ~15) | ((wu&15) ^ (r&15)); \
      uint2 val; val.x = pk2(BK[j][0],BK[j][1]); val.y = pk2(BK[j][2],BK[j][3]); \
      *(uint2*)&Ds[r*256 + p*8 + wh] = val; } }
  #define COMPUTE(s) { \
    _Pragma("unroll") \
    for(int mi=0;mi<4;mi++){ \
      if(mbase + mi*16 < cnt){ \
        uint4 av[8]; \
        _Pragma("unroll") \
        for(int kf=0;kf<8;kf++) av[kf] = *(const uint4*)(Ap[mi] + (size_t)(s)*256 + kf*32); \
        _Pragma("unroll") \
        for(int kf=0;kf<8;kf++){ \
          bf16x8 af = as_bf8(av[kf]); \
          _Pragma("unroll") \
          for(int ni=0;ni<2;ni++){ \
            int R = wn*32 + ni*16 + lr; \
            int v = kf*4 + lg; \
            int vp = (v & ~15) | ((v&15) ^ (R&15)); \
            bf16x8 dfr = *(const bf16x8*)&Ds[R*256 + vp*8]; \
            acc[mi][ni] = __builtin_amdgcn_mfma_f32_16x16x32_bf16(af, dfr, acc[mi][ni], 0,0,0); \
          } \
        } \
      } \
    } }

  const int NS = FFD/256;  // 4
  ISSUE(P, 0, 0)
  ISSUE(Q, 0, 8)
  for(int s=0;s<NS;s++){
    WAITV(8)
    WRITE(P, 0)
    if(s+1<NS){ ISSUE(P, s+1, 0) }
    if(s+1<NS){ WAITV(8) } else { WAITV(0) }
    WRITE(Q, 8)
    if(s+1<NS){ ISSUE(Q, s+1, 8) }
    WAITL0
    __builtin_amdgcn_s_barrier(); SB
    COMPUTE(s)
    __builtin_amdgcn_s_barrier(); SB
  }
  #undef ISSUE
  #undef WRITE
  #undef COMPUTE

  #pragma unroll
  for(int mi=0;mi<4;mi++){
    #pragma unroll
    for(int ni=0;ni<2;ni++){
      int d = nb*64 + wn*32 + ni*16 + lr;
      #pragma unroll
      for(int rg=0;rg<4;rg++){
        int slot = mbase + mi*16 + lg*4 + rg;
        if(slot<cnt){
          int tok = toklist[e*TOK + slot];
          atomicAdd(out + (size_t)tok*DHID + d, acc[mi][ni][rg]);
        }
      }
    }
  }
}

extern "C" void kernel_launch(void* const* d_in, const int* in_sizes, int n_in,
                              void* d_out, int out_size, void* d_ws, size_t ws_size,
                              hipStream_t stream)
{
  (void)in_sizes; (void)n_in; (void)out_size; (void)ws_size;
  const float* x    = (const float*)d_in[0];
  const float* ln1w = (const float*)d_in[1];
  const float* qw   = (const float*)d_in[2];
  const float* kw   = (const float*)d_in[3];
  const float* vw   = (const float*)d_in[4];
  const float* ow   = (const float*)d_in[5];
  const float* qnw  = (const float*)d_in[6];
  const float* knw  = (const float*)d_in[7];
  const float* ln2w = (const float*)d_in[8];
  const float* rw   = (const float*)d_in[9];
  const float* gw   = (const float*)d_in[10];
  const float* uw   = (const float*)d_in[11];
  const float* dwn  = (const float*)d_in[12];
  float* out = (float*)d_out;

  char* p = (char*)d_ws;
  auto alloc = [&](size_t bytes)->void*{ void* r = (void*)p; p += (bytes + 255) & ~(size_t)255; return r; };
  unsigned short* xnb = (unsigned short*)alloc((size_t)TOK*DHID*2);
  float* qf   = (float*)alloc((size_t)TOK*DHID*4);
  float* kf   = (float*)alloc((size_t)TOK*DHID*4);
  float* vf   = (float*)alloc((size_t)TOK*DHID*4);
  float* qh   = (float*)alloc((size_t)TOK*DHID*4);
  float* kh   = (float*)alloc((size_t)TOK*DHID*4);
  float* ctx  = (float*)alloc((size_t)TOK*DHID*4);
  float* hbuf = (float*)alloc((size_t)TOK*DHID*4);
  float* hnf  = (float*)alloc((size_t)TOK*DHID*4);
  unsigned short* hnb = (unsigned short*)alloc((size_t)TOK*DHID*2);
  float* csb  = (float*)alloc((size_t)TOK*64*4);
  float* snb  = (float*)alloc((size_t)TOK*64*4);
  int* counts = (int*)alloc(NEXP*4);
  int* toklist= (int*)alloc((size_t)NEXP*TOK*4);
  float* wlist= (float*)alloc((size_t)NEXP*TOK*4);
  unsigned short* mid = (unsigned short*)alloc((size_t)TOK*KSEL*FFD*2);

  rope_table_kernel<<<64,256,0,stream>>>(csb,snb);
  rms_kernel<<<TOK,256,0,stream>>>(x, ln1w, xnb, nullptr);
  gemm_qkv_kernel<<<dim3(96,4),256,0,stream>>>(xnb,qw,kw,vw,qf,kf,vf);
  qknorm_rope_kernel<<<TOK,256,0,stream>>>(qf,qnw,csb,snb,qh);
  qknorm_rope_kernel<<<TOK,256,0,stream>>>(kf,knw,csb,snb,kh);
  attn_kernel<<<256,256,0,stream>>>(qh,kh,vf,ctx);
  gemm_o_kernel<<<dim3(32,4),256,0,stream>>>(ctx,ow,x,hbuf,out);
  rms_kernel<<<TOK,256,0,stream>>>(hbuf, ln2w, hnb, hnf);
  hipMemsetAsync(counts,0,NEXP*4,stream);
  router_kernel<<<TOK,256,0,stream>>>(hnf,rw,counts,toklist,wlist);
  moe_gateup_kernel<<<dim3(16,NEXP,2),256,0,stream>>>(hnb,gw,uw,counts,toklist,wlist,mid);
  moe_down_kernel<<<dim3(32,NEXP,2),256,0,stream>>>(mid,dwn,counts,toklist,out);
}